// Round 2
// baseline (2454.708 us; speedup 1.0000x reference)
//
#include <hip/hip_runtime.h>

// Elman ReLU RNN, fused persistent kernel, round 2.
// 256 blocks (1 batch/CU) x 192 threads (3 waves):
//   waves 0-1 : h-update (j = tid < 116), W_hh row j in VGPRs; FUSED fc:
//               lanes 0-24 of each wave also compute one W_fc row against the
//               SAME h_{t-1} float4s loaded for the matvec (no extra LDS reads).
//   wave  2   : xp[t+2] = W_ih x[t+2] + b; x read DIRECTLY from global
//               (wave-uniform broadcast loads, L1/L2-served, vmcnt stays in
//               flight across the lgkm-only barrier). No x in LDS at all.
// LDS traffic/step = 58 ds_read_b128 (the 2-consumer floor) + ~6 small ops.
// One lgkm-only barrier per step; f32 throughout (recurrence amplifies
// per-step noise ~1e3x, so bf16 anywhere in the loop would blow the 2.6e-2
// threshold).

namespace {
constexpr int kB = 256;
constexpr int kT = 2048;
constexpr int kI = 50;
constexpr int kH = 116;
constexpr int kO = 50;
}

struct Smem {
  alignas(16) float h[2][128];    // h double buffer (parity t&1)
  alignas(16) float xp[4][128];   // xp ring, slot t&3 holds xp[t]
};

struct XBuf {
  float2 v[25];  // one x row (50 floats); rows are 8B-aligned (200B pitch)
};

__device__ __forceinline__ void sync_lds() {
  // Drains LDS only; global loads/stores (x prefetch, fc output) stay in
  // flight across the barrier.
  __asm__ __volatile__("s_waitcnt lgkmcnt(0)\n\ts_barrier" ::: "memory");
}

__device__ __forceinline__ void x_load(XBuf& xbuf, const float* xrow) {
  const float2* p = (const float2*)xrow;
#pragma unroll
  for (int i = 0; i < 25; ++i) xbuf.v[i] = p[i];
}

// Fused h-update + fc over the shared h_{t-1} loads. All lanes of the wave
// issue both FMA streams; exec masks pick who stores what.
__device__ __forceinline__ void hfc_step(Smem& sm, int t, const float (&wh)[kH],
                                         const float (&wf)[kH], float bfc,
                                         int j, bool is_h, bool do_fc,
                                         float* __restrict__ ob, int fcRow) {
  const int pw = t & 1, pr = pw ^ 1;
  const float4* hp = (const float4*)sm.h[pr];
  float a0 = is_h ? sm.xp[t & 3][j] : 0.f;
  float a1 = 0.f, a2 = 0.f, a3 = 0.f;
  float c0 = bfc, c1 = 0.f, c2 = 0.f, c3 = 0.f;
#pragma unroll
  for (int i = 0; i < kH / 4; ++i) {
    float4 v = hp[i];
    a0 = fmaf(wh[4 * i + 0], v.x, a0);
    a1 = fmaf(wh[4 * i + 1], v.y, a1);
    a2 = fmaf(wh[4 * i + 2], v.z, a2);
    a3 = fmaf(wh[4 * i + 3], v.w, a3);
    c0 = fmaf(wf[4 * i + 0], v.x, c0);
    c1 = fmaf(wf[4 * i + 1], v.y, c1);
    c2 = fmaf(wf[4 * i + 2], v.z, c2);
    c3 = fmaf(wf[4 * i + 3], v.w, c3);
  }
  if (is_h) {
    float hn = (a0 + a1) + (a2 + a3);
    sm.h[pw][j] = hn > 0.f ? hn : 0.f;
  }
  if (do_fc && t > 0) {
    ob[(size_t)(t - 1) * kO + fcRow] = (c0 + c1) + (c2 + c3);
  }
}

__device__ __forceinline__ void xp_compute(Smem& sm, int slot, const XBuf& xc,
                                           const float (&wi0)[kI],
                                           const float (&wi1)[kI], float bias0,
                                           float bias1, int ln) {
  float s00 = 0.f, s01 = 0.f, s02 = 0.f, s03 = 0.f;
  float s10 = 0.f, s11 = 0.f, s12 = 0.f, s13 = 0.f;
#pragma unroll
  for (int i = 0; i < 12; ++i) {
    float2 p = xc.v[2 * i];
    float2 q = xc.v[2 * i + 1];
    s00 = fmaf(wi0[4 * i + 0], p.x, s00);
    s01 = fmaf(wi0[4 * i + 1], p.y, s01);
    s02 = fmaf(wi0[4 * i + 2], q.x, s02);
    s03 = fmaf(wi0[4 * i + 3], q.y, s03);
    s10 = fmaf(wi1[4 * i + 0], p.x, s10);
    s11 = fmaf(wi1[4 * i + 1], p.y, s11);
    s12 = fmaf(wi1[4 * i + 2], q.x, s12);
    s13 = fmaf(wi1[4 * i + 3], q.y, s13);
  }
  float2 pt = xc.v[24];
  s00 = fmaf(wi0[48], pt.x, s00);
  s01 = fmaf(wi0[49], pt.y, s01);
  s10 = fmaf(wi1[48], pt.x, s10);
  s11 = fmaf(wi1[49], pt.y, s11);
  sm.xp[slot][ln] = bias0 + ((s00 + s01) + (s02 + s03));
  if (ln < kH - 64) sm.xp[slot][64 + ln] = bias1 + ((s10 + s11) + (s12 + s13));
}

__launch_bounds__(192, 1)
__global__ void rnn_fused(const float* __restrict__ x,
                          const float* __restrict__ W_ih,
                          const float* __restrict__ b_ih,
                          const float* __restrict__ W_hh,
                          const float* __restrict__ b_hh,
                          const float* __restrict__ W_fc,
                          const float* __restrict__ b_fc,
                          float* __restrict__ out) {
  __shared__ Smem sm;
  const int tid = threadIdx.x;
  const int wv = tid >> 6;
  const int ln = tid & 63;
  const int b = blockIdx.x;
  const float* xb = x + (size_t)b * (kT * kI);
  float* ob = out + (size_t)b * (kT * kO);

  if (wv < 2) {
    // ---- h + fc waves ----
    float wh[kH], wf[kH];
    float bfc = 0.f;
    const int j = tid;
    const bool is_h = (j < kH);
    const bool do_fc = (ln < 25);
    const int fcRow = (wv == 0) ? ln : 25 + ln;

    if (is_h) {
      const float4* wr = (const float4*)(W_hh + j * kH);  // 464B rows, 16B aligned
#pragma unroll
      for (int i = 0; i < kH / 4; ++i) {
        float4 v = wr[i];
        wh[4 * i + 0] = v.x; wh[4 * i + 1] = v.y;
        wh[4 * i + 2] = v.z; wh[4 * i + 3] = v.w;
      }
    } else {
#pragma unroll
      for (int i = 0; i < kH; ++i) wh[i] = 0.f;
    }
    if (do_fc) {
      const float4* wr = (const float4*)(W_fc + fcRow * kH);
#pragma unroll
      for (int i = 0; i < kH / 4; ++i) {
        float4 v = wr[i];
        wf[4 * i + 0] = v.x; wf[4 * i + 1] = v.y;
        wf[4 * i + 2] = v.z; wf[4 * i + 3] = v.w;
      }
      bfc = b_fc[fcRow];
    } else {
#pragma unroll
      for (int i = 0; i < kH; ++i) wf[i] = 0.f;
    }
    if (tid < 128) sm.h[1][tid] = 0.f;  // h[-1] = 0 at parity 1
    sync_lds();

    for (int t = 0; t < kT; t += 2) {
      hfc_step(sm, t + 0, wh, wf, bfc, j, is_h, do_fc, ob, fcRow);
      sync_lds();
      hfc_step(sm, t + 1, wh, wf, bfc, j, is_h, do_fc, ob, fcRow);
      sync_lds();
    }

    // out[kT-1] from h[(kT-1)&1] = h[1]
    if (do_fc) {
      const float4* hp = (const float4*)sm.h[(kT - 1) & 1];
      float c0 = bfc, c1 = 0.f, c2 = 0.f, c3 = 0.f;
#pragma unroll
      for (int i = 0; i < kH / 4; ++i) {
        float4 v = hp[i];
        c0 = fmaf(wf[4 * i + 0], v.x, c0);
        c1 = fmaf(wf[4 * i + 1], v.y, c1);
        c2 = fmaf(wf[4 * i + 2], v.z, c2);
        c3 = fmaf(wf[4 * i + 3], v.w, c3);
      }
      ob[(size_t)(kT - 1) * kO + fcRow] = (c0 + c1) + (c2 + c3);
    }
  } else {
    // ---- xp wave: rows ln and ln+64; x streamed from global ----
    float wi0[kI], wi1[kI];
    float bias0 = 0.f, bias1 = 0.f;
    {
      const float2* wr = (const float2*)(W_ih + ln * kI);  // 200B rows, 8B aligned
#pragma unroll
      for (int i = 0; i < kI / 2; ++i) {
        float2 v = wr[i]; wi0[2 * i] = v.x; wi0[2 * i + 1] = v.y;
      }
      bias0 = b_ih[ln] + b_hh[ln];
    }
    if (ln < kH - 64) {
      const float2* wr = (const float2*)(W_ih + (ln + 64) * kI);
#pragma unroll
      for (int i = 0; i < kI / 2; ++i) {
        float2 v = wr[i]; wi1[2 * i] = v.x; wi1[2 * i + 1] = v.y;
      }
      bias1 = b_ih[ln + 64] + b_hh[ln + 64];
    } else {
#pragma unroll
      for (int i = 0; i < kI; ++i) wi1[i] = 0.f;
      bias1 = 0.f;
    }

    XBuf A, B;
    x_load(A, xb + 0 * kI);
    x_load(B, xb + 1 * kI);
    xp_compute(sm, 0, A, wi0, wi1, bias0, bias1, ln);  // xp[0]
    xp_compute(sm, 1, B, wi0, wi1, bias0, bias1, ln);  // xp[1]
    x_load(A, xb + 2 * kI);  // for xp[2] at t=0
    x_load(B, xb + 3 * kI);  // for xp[3] at t=1
    sync_lds();

    for (int t = 0; t < kT; t += 2) {
      // even step: xp[t+2] from A; refill A <- x[t+4]
      xp_compute(sm, (t + 2) & 3, A, wi0, wi1, bias0, bias1, ln);
      {
        int tf = t + 4; tf = tf < kT ? tf : kT - 1;
        x_load(A, xb + (size_t)tf * kI);
      }
      sync_lds();
      // odd step: xp[t+3] from B; refill B <- x[t+5]
      xp_compute(sm, (t + 3) & 3, B, wi0, wi1, bias0, bias1, ln);
      {
        int tf = t + 5; tf = tf < kT ? tf : kT - 1;
        x_load(B, xb + (size_t)tf * kI);
      }
      sync_lds();
    }
  }
}

extern "C" void kernel_launch(void* const* d_in, const int* in_sizes, int n_in,
                              void* d_out, int out_size, void* d_ws, size_t ws_size,
                              hipStream_t stream) {
  (void)in_sizes; (void)n_in; (void)d_ws; (void)ws_size; (void)out_size;
  const float* x    = (const float*)d_in[0];
  const float* W_ih = (const float*)d_in[1];
  const float* b_ih = (const float*)d_in[2];
  const float* W_hh = (const float*)d_in[3];
  const float* b_hh = (const float*)d_in[4];
  const float* W_fc = (const float*)d_in[5];
  const float* b_fc = (const float*)d_in[6];
  float* out = (float*)d_out;
  rnn_fused<<<dim3(kB), dim3(192), 0, stream>>>(x, W_ih, b_ih, W_hh, b_hh,
                                                W_fc, b_fc, out);
}

// Round 3
// 1890.737 us; speedup vs baseline: 1.2983x; 1.2983x over previous
//
#include <hip/hip_runtime.h>

// Elman ReLU RNN, fused persistent kernel, round 3.
// 256 blocks (1 batch/CU) x 192 threads (3 waves):
//   waves 0-1 : h-update (j = tid < 116), W_hh row j in VGPRs (float4 wh4[29]).
//               FUSED fc with k-split: lanes ln<50 of wave 0 hold chunks [0,14)
//               (56 floats) of W_fc row ln; wave 1 holds chunks [14,29)
//               (60 floats). Both partial-dot against the SAME h_{t-1} float4s
//               loaded for the matvec (zero extra ds_read_b128), write partials
//               to a double-buffered LDS strip.
//   wave  2   : xp[t+2] = W_ih x[t+2] + b (x direct from global, single 50-float
//               buffer, distance-1 prefetch) + combines the two fc partials from
//               step t-1 (+b_fc) and stores out[t-2].
// Register budget is the r2 lesson: worst lane ~200 VGPRs (116+60+temps), under
// the proven-safe zone; r2's 232+ demand made the allocator re-materialize
// weights from global every step (FETCH doubled).
// LDS/step = 58 ds_read_b128 (2-consumer floor) + ~10 b32. One lgkm-only
// barrier per step (global x loads / out stores never drained at the barrier).
// f32 throughout: recurrence amplifies per-step noise ~1e3-1e4x; bf16 anywhere
// in the loop blows the 2.6e-2 threshold.

namespace {
constexpr int kB = 256;
constexpr int kT = 2048;
constexpr int kI = 50;
constexpr int kH = 116;
constexpr int kO = 50;
}

struct Smem {
  alignas(16) float h[2][128];      // h double buffer (parity t&1)
  alignas(16) float xp[4][128];     // xp ring, slot t&3 holds xp[t]
  alignas(16) float fcp[2][2][64];  // [parity][k-half][row] fc partials
};

__device__ __forceinline__ void sync_lds() {
  // Drains LDS only; global loads/stores stay in flight across the barrier.
  __asm__ __volatile__("s_waitcnt lgkmcnt(0)\n\ts_barrier" ::: "memory");
}

// ---------------- h + fused-fc waves ----------------
template <int CB, int CE>
__device__ __forceinline__ void run_h(Smem& sm,
                                      const float* __restrict__ W_hh,
                                      const float* __restrict__ W_fc,
                                      int j, int ln) {
  constexpr int half = (CB == 0) ? 0 : 1;
  const bool is_h = (j < kH);
  const bool do_fc = (ln < kO);

  float4 wh4[29];
  if (is_h) {
    const float4* wr = (const float4*)(W_hh + j * kH);  // 464B rows, 16B aligned
#pragma unroll
    for (int i = 0; i < 29; ++i) wh4[i] = wr[i];
  } else {
#pragma unroll
    for (int i = 0; i < 29; ++i) wh4[i] = make_float4(0.f, 0.f, 0.f, 0.f);
  }
  float4 wf4[CE - CB];
  if (do_fc) {
    const float4* wr = (const float4*)(W_fc + ln * kH);
#pragma unroll
    for (int i = CB; i < CE; ++i) wf4[i - CB] = wr[i];
  } else {
#pragma unroll
    for (int i = 0; i < CE - CB; ++i) wf4[i] = make_float4(0.f, 0.f, 0.f, 0.f);
  }
  sm.h[1][j] = 0.f;  // h[-1] = 0 lives at parity (0-1)&1 = 1; j covers 0..127
  sync_lds();        // barrier #1 (matches run_xp's)

  for (int t = 0; t < kT; ++t) {
    const int pw = t & 1, pr = pw ^ 1;
    const float4* hp = (const float4*)sm.h[pr];
    float a0 = sm.xp[t & 3][j];  // garbage for j>=116, discarded below
    float a1 = 0.f, a2 = 0.f, a3 = 0.f;
    float c0 = 0.f, c1 = 0.f, c2 = 0.f, c3 = 0.f;
#pragma unroll
    for (int i = 0; i < 29; ++i) {
      const float4 v = hp[i];
      a0 = fmaf(wh4[i].x, v.x, a0);
      a1 = fmaf(wh4[i].y, v.y, a1);
      a2 = fmaf(wh4[i].z, v.z, a2);
      a3 = fmaf(wh4[i].w, v.w, a3);
      if (i >= CB && i < CE) {  // compile-time after unroll
        const float4 w = wf4[i - CB];
        c0 = fmaf(w.x, v.x, c0);
        c1 = fmaf(w.y, v.y, c1);
        c2 = fmaf(w.z, v.z, c2);
        c3 = fmaf(w.w, v.w, c3);
      }
    }
    if (is_h) {
      const float hn = (a0 + a1) + (a2 + a3);
      sm.h[pw][j] = hn > 0.f ? hn : 0.f;
    }
    if (do_fc) sm.fcp[t & 1][half][ln] = (c0 + c1) + (c2 + c3);
    sync_lds();
  }

  // tail: fc partials on h[kT-1] (parity 1) -> fcp[kT&1] = fcp[0]
  {
    const float4* hp = (const float4*)sm.h[(kT - 1) & 1];
    float c0 = 0.f, c1 = 0.f, c2 = 0.f, c3 = 0.f;
#pragma unroll
    for (int i = CB; i < CE; ++i) {
      const float4 v = hp[i];
      const float4 w = wf4[i - CB];
      c0 = fmaf(w.x, v.x, c0);
      c1 = fmaf(w.y, v.y, c1);
      c2 = fmaf(w.z, v.z, c2);
      c3 = fmaf(w.w, v.w, c3);
    }
    if (do_fc) sm.fcp[kT & 1][half][ln] = (c0 + c1) + (c2 + c3);
    sync_lds();  // matches run_xp tail barrier
  }
}

// ---------------- xp + fc-combine wave ----------------
__device__ __forceinline__ void x_load(float2 (&X)[25], const float* xrow) {
  const float2* p = (const float2*)xrow;  // x rows 200B pitch, 8B aligned
#pragma unroll
  for (int i = 0; i < 25; ++i) X[i] = p[i];
}

__device__ __forceinline__ void xp_compute(Smem& sm, int slot,
                                           const float2 (&X)[25],
                                           const float (&wi0)[kI],
                                           const float (&wi1)[kI], float bias0,
                                           float bias1, int ln) {
  float s00 = 0.f, s01 = 0.f, s02 = 0.f, s03 = 0.f;
  float s10 = 0.f, s11 = 0.f, s12 = 0.f, s13 = 0.f;
#pragma unroll
  for (int i = 0; i < 12; ++i) {
    const float2 p = X[2 * i];
    const float2 q = X[2 * i + 1];
    s00 = fmaf(wi0[4 * i + 0], p.x, s00);
    s01 = fmaf(wi0[4 * i + 1], p.y, s01);
    s02 = fmaf(wi0[4 * i + 2], q.x, s02);
    s03 = fmaf(wi0[4 * i + 3], q.y, s03);
    s10 = fmaf(wi1[4 * i + 0], p.x, s10);
    s11 = fmaf(wi1[4 * i + 1], p.y, s11);
    s12 = fmaf(wi1[4 * i + 2], q.x, s12);
    s13 = fmaf(wi1[4 * i + 3], q.y, s13);
  }
  const float2 pt = X[24];
  s00 = fmaf(wi0[48], pt.x, s00);
  s01 = fmaf(wi0[49], pt.y, s01);
  s10 = fmaf(wi1[48], pt.x, s10);
  s11 = fmaf(wi1[49], pt.y, s11);
  sm.xp[slot][ln] = bias0 + ((s00 + s01) + (s02 + s03));
  if (ln < kH - 64) sm.xp[slot][64 + ln] = bias1 + ((s10 + s11) + (s12 + s13));
}

__device__ __forceinline__ void run_xp(Smem& sm, const float* __restrict__ xb,
                                       const float* __restrict__ W_ih,
                                       const float* __restrict__ b_ih,
                                       const float* __restrict__ b_hh,
                                       const float* __restrict__ b_fc,
                                       float* __restrict__ ob, int ln) {
  float wi0[kI], wi1[kI];
  float bias0, bias1 = 0.f, bfc = 0.f;
  {
    const float2* wr = (const float2*)(W_ih + ln * kI);  // 200B rows, 8B aligned
#pragma unroll
    for (int i = 0; i < 25; ++i) { wi0[2 * i] = wr[i].x; wi0[2 * i + 1] = wr[i].y; }
    bias0 = b_ih[ln] + b_hh[ln];
  }
  if (ln < kH - 64) {
    const float2* wr = (const float2*)(W_ih + (ln + 64) * kI);
#pragma unroll
    for (int i = 0; i < 25; ++i) { wi1[2 * i] = wr[i].x; wi1[2 * i + 1] = wr[i].y; }
    bias1 = b_ih[ln + 64] + b_hh[ln + 64];
  } else {
#pragma unroll
    for (int i = 0; i < kI; ++i) wi1[i] = 0.f;
  }
  if (ln < kO) bfc = b_fc[ln];

  float2 X[25];
  x_load(X, xb + 0 * kI);
  xp_compute(sm, 0, X, wi0, wi1, bias0, bias1, ln);
  x_load(X, xb + 1 * kI);
  xp_compute(sm, 1, X, wi0, wi1, bias0, bias1, ln);
  x_load(X, xb + 2 * kI);  // consumed at t=0
  sync_lds();              // barrier #1

  for (int t = 0; t < kT; ++t) {
    xp_compute(sm, (t + 2) & 3, X, wi0, wi1, bias0, bias1, ln);
    const int tf = (t + 3 < kT) ? (t + 3) : (kT - 1);
    x_load(X, xb + (size_t)tf * kI);  // distance-1 prefetch, vmcnt in flight
    if (ln < kO && t >= 2) {
      const int pp = (t - 1) & 1;
      const float p = sm.fcp[pp][0][ln] + sm.fcp[pp][1][ln] + bfc;
      ob[(size_t)(t - 2) * kO + ln] = p;  // out[t-2], global store non-blocking
    }
    sync_lds();
  }

  // tail: partials for out[kT-2] are in fcp[1] (written at step kT-1);
  // h-waves concurrently write fcp[0] from h[kT-1] (disjoint) before barrier.
  if (ln < kO) {
    const float p = sm.fcp[1][0][ln] + sm.fcp[1][1][ln] + bfc;
    ob[(size_t)(kT - 2) * kO + ln] = p;
  }
  sync_lds();
  if (ln < kO) {
    const float p = sm.fcp[0][0][ln] + sm.fcp[0][1][ln] + bfc;
    ob[(size_t)(kT - 1) * kO + ln] = p;
  }
}

__launch_bounds__(192, 1)
__global__ void rnn_fused(const float* __restrict__ x,
                          const float* __restrict__ W_ih,
                          const float* __restrict__ b_ih,
                          const float* __restrict__ W_hh,
                          const float* __restrict__ b_hh,
                          const float* __restrict__ W_fc,
                          const float* __restrict__ b_fc,
                          float* __restrict__ out) {
  __shared__ Smem sm;
  const int tid = threadIdx.x;
  const int wv = tid >> 6;
  const int ln = tid & 63;
  const int b = blockIdx.x;
  const float* xb = x + (size_t)b * (kT * kI);
  float* ob = out + (size_t)b * (kT * kO);

  if (wv == 0) {
    run_h<0, 14>(sm, W_hh, W_fc, tid, ln);
  } else if (wv == 1) {
    run_h<14, 29>(sm, W_hh, W_fc, tid, ln);
  } else {
    run_xp(sm, xb, W_ih, b_ih, b_hh, b_fc, ob, ln);
  }
}

extern "C" void kernel_launch(void* const* d_in, const int* in_sizes, int n_in,
                              void* d_out, int out_size, void* d_ws, size_t ws_size,
                              hipStream_t stream) {
  (void)in_sizes; (void)n_in; (void)d_ws; (void)ws_size; (void)out_size;
  const float* x    = (const float*)d_in[0];
  const float* W_ih = (const float*)d_in[1];
  const float* b_ih = (const float*)d_in[2];
  const float* W_hh = (const float*)d_in[3];
  const float* b_hh = (const float*)d_in[4];
  const float* W_fc = (const float*)d_in[5];
  const float* b_fc = (const float*)d_in[6];
  float* out = (float*)d_out;
  rnn_fused<<<dim3(kB), dim3(192), 0, stream>>>(x, W_ih, b_ih, W_hh, b_hh,
                                                W_fc, b_fc, out);
}